// Round 18
// baseline (499.114 us; speedup 1.0000x reference)
//
#include <hip/hip_runtime.h>
#include <stdint.h>

#define BB 4096
#define TT 512
#define HH 32
#define SS 4

__device__ __forceinline__ float fast_sigm(float a) {
  return __builtin_amdgcn_rcpf(1.0f + __expf(-a));      // v_exp + v_rcp
}
__device__ __forceinline__ float fast_tanh(float y) {
  return 1.0f - 2.0f * __builtin_amdgcn_rcpf(__expf(2.0f * y) + 1.0f);
}

// pack two f32 -> f16 pair (RTZ; validated r17, absmax 3.9e-3)
#define PKH(dst, lo, hi)                                                       \
  asm volatile("v_cvt_pkrtz_f16_f32 %0, %1, %2" : "=v"(dst) : "v"(lo), "v"(hi))
// AGPR write/read (validated r15). RD is volatile so per-step reads are NOT
// CSE-hoisted into loop-invariant arch regs (which would recreate the spill).
#define WRA(idx, val)                                                          \
  asm volatile("v_accvgpr_write_b32 %0, %1" : "=a"(awp[idx]) : "v"(val))
#define RD(dst, idx)                                                           \
  asm volatile("v_accvgpr_read_b32 %0, %1" : "=v"(dst) : "a"(awp[idx]))
#define RDF(dst, idx)                                                          \
  { uint32_t t_; RD(t_, idx); (dst) = __uint_as_float(t_); }

// mixed FMA: acc(f32) += f16half(w) * f32(h)  (validated r17)
#define MIXLO(acc, w, h)                                                       \
  asm("v_fma_mix_f32 %0, %1, %2, %0 op_sel:[0,0,0] op_sel_hi:[1,0,0]"          \
      : "+v"(acc) : "v"(w), "v"(h))
#define MIXHI(acc, w, h)                                                       \
  asm("v_fma_mix_f32 %0, %1, %2, %0 op_sel:[1,0,0] op_sel_hi:[1,0,0]"          \
      : "+v"(acc) : "v"(w), "v"(h))

// read the 6 packed weights of chunk c (r,z,n gates)
#define RD6(b0, b1, b2, b3, b4, b5, c)                                         \
  RD(b0, 2*(c)); RD(b1, 2*(c)+1); RD(b2, 16+2*(c)); RD(b3, 17+2*(c));         \
  RD(b4, 32+2*(c)); RD(b5, 33+2*(c))

// 12 fma_mix of chunk c, r/z/n interleaved (3 independent acc chains)
#define MIX12(h, r0, r1, z0, z1, n0, n1)                                       \
  MIXLO(accr, r0, (h).x); MIXLO(accz, z0, (h).x); MIXLO(accn, n0, (h).x);      \
  MIXHI(accr, r0, (h).y); MIXHI(accz, z0, (h).y); MIXHI(accn, n0, (h).y);      \
  MIXLO(accr, r1, (h).z); MIXLO(accz, z1, (h).z); MIXLO(accn, n1, (h).z);      \
  MIXHI(accr, r1, (h).w); MIXHI(accz, z1, (h).w); MIXHI(accn, n1, (h).w)

// Champion structure (2 batches/wave, LDS h rows, deferred proj) with ALL
// parameters f16-packed in AGPRs — the one storage class the allocator never
// spills (r15). GEMV: 48 pipelined AGPR reads + 96 fma_mix; h-quads read from
// LDS with lead-2 (only 3 quads live). Nothing loop-invariant remains in arch
// VGPRs -> nothing to spill; arch pressure ~55.
__global__ void __launch_bounds__(256, 2)
gru_kernel(const float* __restrict__ x, const float* __restrict__ h0,
           const float* __restrict__ w_ih, const float* __restrict__ w_hh,
           const float* __restrict__ b_ih, const float* __restrict__ b_hh,
           const float* __restrict__ w_proj, const float* __restrict__ b_proj,
           float* __restrict__ out) {
  const int tid  = threadIdx.x;
  const int wid  = tid >> 6;        // wave 0..3
  const int lane = tid & 63;
  const int g    = lane >> 5;       // batch within wave
  const int j    = lane & 31;       // h index owned by this lane
  const int row  = wid * 2 + g;     // LDS h row 0..7
  const int b    = blockIdx.x * 8 + row;
  const int s_idx = j & 3;          // proj channel
  const int c_idx = j >> 2;         // proj h-chunk

  __shared__ float lds_h[8][36];    // 144B row stride (conflict-free, r5-r17)
  float* lrow = &lds_h[row][0];
  const float4* lrow4 = (const float4*)lrow;
  const float* hc_addr = lrow + (c_idx << 2);

  // ---- pack ALL parameters into AGPRs ----
  // layout: 0..15 wr | 16..31 wz | 32..47 wn | 48..53 w_ih | 54..55 w_proj
  //         56..58 b_ih(r,z,n) | 59..61 b_hh(r,z,n) | 62 b_proj
  uint32_t awp[64];
  {
    const float4* whh4 = (const float4*)w_hh;
#pragma unroll
    for (int c = 0; c < 8; ++c) {
      const float4 tr = whh4[(0 * HH + j) * 8 + c];
      const float4 tz = whh4[(1 * HH + j) * 8 + c];
      const float4 tn = whh4[(2 * HH + j) * 8 + c];
      uint32_t p0, p1;
      PKH(p0, tr.x, tr.y); PKH(p1, tr.z, tr.w);
      WRA(2*c, p0); WRA(2*c+1, p1);
      PKH(p0, tz.x, tz.y); PKH(p1, tz.z, tz.w);
      WRA(16+2*c, p0); WRA(17+2*c, p1);
      PKH(p0, tn.x, tn.y); PKH(p1, tn.z, tn.w);
      WRA(32+2*c, p0); WRA(33+2*c, p1);
    }
    const float4* wih4 = (const float4*)w_ih;
    const float4 a = wih4[j], bq = wih4[32 + j], cq = wih4[64 + j];
    uint32_t p;
    PKH(p, a.x,  a.y);  WRA(48, p);
    PKH(p, a.z,  a.w);  WRA(49, p);
    PKH(p, bq.x, bq.y); WRA(50, p);
    PKH(p, bq.z, bq.w); WRA(51, p);
    PKH(p, cq.x, cq.y); WRA(52, p);
    PKH(p, cq.z, cq.w); WRA(53, p);
    const float4 pq = ((const float4*)w_proj)[s_idx * 8 + c_idx];
    PKH(p, pq.x, pq.y); WRA(54, p);
    PKH(p, pq.z, pq.w); WRA(55, p);
    WRA(56, __float_as_uint(b_ih[j]));
    WRA(57, __float_as_uint(b_ih[32 + j]));
    WRA(58, __float_as_uint(b_ih[64 + j]));
    WRA(59, __float_as_uint(b_hh[j]));
    WRA(60, __float_as_uint(b_hh[32 + j]));
    WRA(61, __float_as_uint(b_hh[64 + j]));
    WRA(62, __float_as_uint(b_proj[s_idx]));
  }

  float h_self = h0[(size_t)b * HH + j];
  lrow[j] = h_self;

  const float4* xp = (const float4*)(x + (size_t)b * TT * 4);
  float* outp = out + (size_t)b * TT * SS;

  float4 xv = xp[0];

  for (int t = 0; t <= TT; ++t) {
    // ---- deferred projection: out[t-1] = proj(h after step t-1) ----
    const float4 hcv = *(const float4*)hc_addr;
    if (t > 0) {
      uint32_t wpp0, wpp1; float bp_;
      RD(wpp0, 54); RD(wpp1, 55); RDF(bp_, 62);
      float v = 0.0f;
      MIXLO(v, wpp0, hcv.x); MIXHI(v, wpp0, hcv.y);
      MIXLO(v, wpp1, hcv.z); MIXHI(v, wpp1, hcv.w);
      v += __shfl_xor(v, 4, 64);
      v += __shfl_xor(v, 8, 64);
      v += __shfl_xor(v, 16, 64);
      if (c_idx == 0) outp[(t - 1) * SS + s_idx] = v + bp_;
    }
    if (t == TT) break;

    float4 xvn = xp[(t + 1 < TT) ? (t + 1) : t];   // next-step x prefetch

    // ---- input gates: 6 packed weights + 3 biases from AGPR, 12 fma_mix ----
    uint32_t wi0, wi1, wi2, wi3, wi4, wi5;
    RD(wi0, 48); RD(wi1, 49); RD(wi2, 50); RD(wi3, 51); RD(wi4, 52); RD(wi5, 53);
    float xr, xz, xn;
    RDF(xr, 56); RDF(xz, 57); RDF(xn, 58);
    MIXLO(xr, wi0, xv.x); MIXHI(xr, wi0, xv.y);
    MIXLO(xr, wi1, xv.z); MIXHI(xr, wi1, xv.w);
    MIXLO(xz, wi2, xv.x); MIXHI(xz, wi2, xv.y);
    MIXLO(xz, wi3, xv.z); MIXHI(xz, wi3, xv.w);
    MIXLO(xn, wi4, xv.x); MIXHI(xn, wi4, xv.y);
    MIXLO(xn, wi5, xv.z); MIXHI(xn, wi5, xv.w);

    // ---- hidden GEMV: pipelined (weights lead 1 chunk, h-quads lead 2) ----
    float accr, accz, accn;
    RDF(accr, 59); RDF(accz, 60); RDF(accn, 61);

    uint32_t wa0, wa1, wa2, wa3, wa4, wa5, wb0, wb1, wb2, wb3, wb4, wb5;
    float4 q0 = lrow4[0], q1 = lrow4[1];
    RD6(wa0, wa1, wa2, wa3, wa4, wa5, 0);
    float4 q2 = lrow4[2];
    RD6(wb0, wb1, wb2, wb3, wb4, wb5, 1);
    MIX12(q0, wa0, wa1, wa2, wa3, wa4, wa5);
    float4 q3 = lrow4[3];
    RD6(wa0, wa1, wa2, wa3, wa4, wa5, 2);
    MIX12(q1, wb0, wb1, wb2, wb3, wb4, wb5);
    float4 q4 = lrow4[4];
    RD6(wb0, wb1, wb2, wb3, wb4, wb5, 3);
    MIX12(q2, wa0, wa1, wa2, wa3, wa4, wa5);
    float4 q5 = lrow4[5];
    RD6(wa0, wa1, wa2, wa3, wa4, wa5, 4);
    MIX12(q3, wb0, wb1, wb2, wb3, wb4, wb5);
    float4 q6 = lrow4[6];
    RD6(wb0, wb1, wb2, wb3, wb4, wb5, 5);
    MIX12(q4, wa0, wa1, wa2, wa3, wa4, wa5);
    float4 q7 = lrow4[7];
    RD6(wa0, wa1, wa2, wa3, wa4, wa5, 6);
    MIX12(q5, wb0, wb1, wb2, wb3, wb4, wb5);
    RD6(wb0, wb1, wb2, wb3, wb4, wb5, 7);
    MIX12(q6, wa0, wa1, wa2, wa3, wa4, wa5);
    MIX12(q7, wb0, wb1, wb2, wb3, wb4, wb5);

    // ---- gates + h update ----
    const float r  = fast_sigm(xr + accr);
    const float zz = fast_sigm(xz + accz);
    const float nn = fast_tanh(fmaf(r, accn, xn));
    const float hnew = fmaf(zz, h_self - nn, nn);  // (1-z)n + z h
    h_self = hnew;

    lrow[j] = hnew;   // publish h_t (same-wave, in-order DS pipe)

    xv = xvn;
  }

  // hn output: [1, B, H] appended after state (f32)
  out[(size_t)BB * TT * SS + (size_t)b * HH + j] = h_self;
}

extern "C" void kernel_launch(void* const* d_in, const int* in_sizes, int n_in,
                              void* d_out, int out_size, void* d_ws, size_t ws_size,
                              hipStream_t stream) {
  const float* x      = (const float*)d_in[0];
  const float* h0     = (const float*)d_in[1];
  const float* w_ih   = (const float*)d_in[2];
  const float* w_hh   = (const float*)d_in[3];
  const float* b_ih   = (const float*)d_in[4];
  const float* b_hh   = (const float*)d_in[5];
  const float* w_proj = (const float*)d_in[6];
  const float* b_proj = (const float*)d_in[7];
  float* out = (float*)d_out;

  dim3 grid(BB / 8), block(256);
  hipLaunchKernelGGL(gru_kernel, grid, block, 0, stream,
                     x, h0, w_ih, w_hh, b_ih, b_hh, w_proj, b_proj, out);
}